// Round 1
// baseline (371.846 us; speedup 1.0000x reference)
//
#include <hip/hip_runtime.h>

#define BATCH 8
#define NPTS 4096
#define NROWS (BATCH*NPTS)   // 32768
#define KNB 16
#define NC 128

typedef __attribute__((ext_vector_type(8))) short bf16x8;
typedef __attribute__((ext_vector_type(4))) float f32x4;

static __device__ __forceinline__ unsigned short f2bf(float f) {
  unsigned u = __float_as_uint(f);
  u = u + 0x7fffu + ((u >> 16) & 1u);   // round-to-nearest-even
  return (unsigned short)(u >> 16);
}

// ---------------------------------------------------------------- prep
// xyzw[i] = (x,y,z,|p|^2), W1/W2 -> bf16
__global__ __launch_bounds__(256) void prep_kernel(
    const float* __restrict__ xyz, const float* __restrict__ W1,
    const float* __restrict__ W2, float4* __restrict__ xyzw,
    unsigned short* __restrict__ W1bf, unsigned short* __restrict__ W2bf)
{
  int i = blockIdx.x * 256 + threadIdx.x;
  if (i < NROWS) {
    #pragma clang fp contract(off)
    float x = xyz[3*i], y = xyz[3*i+1], z = xyz[3*i+2];
    float sq = x*x + y*y + z*z;
    xyzw[i] = make_float4(x, y, z, sq);
  }
  if (i < NC*NC) {
    W1bf[i] = f2bf(W1[i]);
    W2bf[i] = f2bf(W2[i]);
  }
}

// ---------------------------------------------------------------- topk
// One wave per (b,m). Each lane owns 64 candidates n = j*64+lane.
// Extract the 17 largest (tie-break: smaller n), drop rank 0,
// write coords of ranks 1..16 to grouped4.
__global__ __launch_bounds__(256) void topk_kernel(
    const float4* __restrict__ xyzw, float4* __restrict__ grouped4)
{
  const int lane = threadIdx.x & 63;
  const int wid  = blockIdx.x * 4 + (threadIdx.x >> 6);
  const int b    = wid >> 12;          // /4096
  const int m    = wid & (NPTS - 1);
  const float4* base = xyzw + (size_t)b * NPTS;

  float4 pm = base[m];
  float d[64];
  {
    #pragma clang fp contract(off)
    #pragma unroll
    for (int j = 0; j < 64; ++j) {
      float4 p = base[j*64 + lane];
      float dot = pm.x*p.x + pm.y*p.y + pm.z*p.z;
      d[j] = (pm.w + p.w) - 2.0f*dot;   // matches (sq_m+sq_n) - 2*dot
    }
  }

  // per-lane top-2 (strict >: ties keep smaller j, i.e. smaller n)
  float v1 = -3.0e38f, v2 = -3.0e38f;
  int   i1 = -1,       i2 = -1;
  #pragma unroll
  for (int j = 0; j < 64; ++j) {
    float dj = d[j];
    bool g1 = dj > v1;
    bool g2 = dj > v2;
    float nv2 = g1 ? v1 : (g2 ? dj : v2);
    int   ni2 = g1 ? i1 : (g2 ? j  : i2);
    v1 = g1 ? dj : v1;
    i1 = g1 ? j  : i1;
    v2 = nv2; i2 = ni2;
  }

  unsigned long long taken = 0ull;
  int sel_n = 0;
  #pragma unroll 1
  for (int r = 0; r < KNB + 1; ++r) {
    float mv = v1;
    int   mn = (i1 >= 0) ? ((i1 << 6) | lane) : 0x7FFFFFFF;  // mn == n
    #pragma unroll
    for (int s = 1; s < 64; s <<= 1) {
      float ov = __shfl_xor(mv, s);
      int   on = __shfl_xor(mn, s);
      bool take = (ov > mv) || ((ov == mv) && (on < mn));
      mv = take ? ov : mv;
      mn = take ? on : mn;
    }
    if (r >= 1 && lane == (r - 1)) sel_n = mn;   // ranks 1..16 -> lanes 0..15
    if (((mn & 63) == lane) && r < KNB) {        // this lane won: pop
      taken |= (1ull << i1);
      if (i2 >= 0) {
        v1 = v2; i1 = i2; v2 = -3.0e38f; i2 = -1;   // promote cached 2nd
      } else {
        // rare: recompute top-2 over not-yet-taken candidates
        v1 = -3.0e38f; i1 = -1; v2 = -3.0e38f; i2 = -1;
        #pragma unroll
        for (int j = 0; j < 64; ++j) {
          if (!((taken >> j) & 1ull)) {
            float dj = d[j];
            bool g1 = dj > v1;
            bool g2 = dj > v2;
            float nv2 = g1 ? v1 : (g2 ? dj : v2);
            int   ni2 = g1 ? i1 : (g2 ? j  : i2);
            v1 = g1 ? dj : v1;
            i1 = g1 ? j  : i1;
            v2 = nv2; i2 = ni2;
          }
        }
      }
    }
  }

  if (lane < KNB) {
    grouped4[(size_t)wid * KNB + lane] = base[sel_n];
  }
}

// ---------------------------------------------------------------- mlp
// One block = 8 points = 128 rows. act[128][128] bf16 in LDS, XOR-swizzled
// (ushort idx: r*128 + (c ^ ((r&7)<<3))). Waves own disjoint 32-row slices,
// so after the initial barrier each wave runs layer0->L1->L2 independently.
__global__ __launch_bounds__(256) void mlp_kernel(
    const float4* __restrict__ grouped4,
    const float*  __restrict__ W0, const float* __restrict__ b0,
    const unsigned short* __restrict__ W1bf, const float* __restrict__ b1,
    const unsigned short* __restrict__ W2bf, const float* __restrict__ b2,
    float* __restrict__ out)
{
  __shared__ float4 g4s[128];
  __shared__ float  W0s[128*4];
  __shared__ float  b0s[128], b1s[128], b2s[128];
  __shared__ unsigned short act[128*128];   // 32 KB

  const int t    = threadIdx.x;
  const int lane = t & 63;
  const int w    = t >> 6;
  const int lr   = lane & 15;   // row-in-tile (A) / col-in-tile (B,C)
  const int lg   = lane >> 4;   // k-group / row-group in C
  const int row_base = blockIdx.x * 8;   // 8 points per block

  if (t < 128) {
    g4s[t] = grouped4[(size_t)row_base * KNB + t];
    float4 w0r;
    w0r.x = W0[t*3+0]; w0r.y = W0[t*3+1]; w0r.z = W0[t*3+2]; w0r.w = 0.0f;
    *(float4*)&W0s[t*4] = w0r;
    b0s[t] = b0[t];
    b1s[t] = b1[t];
    b2s[t] = b2[t];
  }
  __syncthreads();

  // ---- layer 0 (fp32 vector, C=3), write act as bf16
  {
    int r  = t >> 1;
    int cb = (t & 1) * 64;
    float4 g = g4s[r];
    int swz = (r & 7) << 3;
    #pragma unroll
    for (int cc = 0; cc < 8; ++cc) {
      int c0 = cb + cc*8;
      unsigned int pk[4];
      #pragma unroll
      for (int pair = 0; pair < 4; ++pair) {
        unsigned int lo, hi;
        {
          int o = c0 + pair*2;
          float v = b0s[o] + g.x*W0s[o*4] + g.y*W0s[o*4+1] + g.z*W0s[o*4+2];
          lo = f2bf(fmaxf(v, 0.0f));
          o++;
          float v2 = b0s[o] + g.x*W0s[o*4] + g.y*W0s[o*4+1] + g.z*W0s[o*4+2];
          hi = f2bf(fmaxf(v2, 0.0f));
        }
        pk[pair] = lo | (hi << 16);
      }
      uint4 q = make_uint4(pk[0], pk[1], pk[2], pk[3]);
      *(uint4*)&act[r*128 + (c0 ^ swz)] = q;
    }
  }
  // no barrier needed: each wave computed exactly its own 32 rows

  const int rt0 = w*2, rt1 = w*2 + 1;
  const int aswz = (lr & 7) << 3;

  // ---- layer 1 (bf16 MFMA), relu, in-place act update
  {
    f32x4 acc[2][8];
    #pragma unroll
    for (int rr = 0; rr < 2; ++rr)
      #pragma unroll
      for (int ct = 0; ct < 8; ++ct)
        acc[rr][ct] = (f32x4){0.f, 0.f, 0.f, 0.f};

    #pragma unroll
    for (int ks = 0; ks < 4; ++ks) {
      int c0 = ks*32 + lg*8;
      bf16x8 a0 = *(const bf16x8*)&act[(rt0*16 + lr)*128 + (c0 ^ aswz)];
      bf16x8 a1 = *(const bf16x8*)&act[(rt1*16 + lr)*128 + (c0 ^ aswz)];
      #pragma unroll
      for (int ct = 0; ct < 8; ++ct) {
        int o = ct*16 + lr;
        bf16x8 bb = *(const bf16x8*)&W1bf[o*128 + c0];
        acc[0][ct] = __builtin_amdgcn_mfma_f32_16x16x32_bf16(a0, bb, acc[0][ct], 0, 0, 0);
        acc[1][ct] = __builtin_amdgcn_mfma_f32_16x16x32_bf16(a1, bb, acc[1][ct], 0, 0, 0);
      }
    }
    #pragma unroll
    for (int rr = 0; rr < 2; ++rr) {
      int rt = rt0 + rr;
      #pragma unroll
      for (int ct = 0; ct < 8; ++ct) {
        int col  = ct*16 + lr;
        float bias = b1s[col];
        #pragma unroll
        for (int i = 0; i < 4; ++i) {
          int row = rt*16 + lg*4 + i;
          float v = acc[rr][ct][i] + bias;
          v = fmaxf(v, 0.0f);
          act[row*128 + (col ^ ((row & 7) << 3))] = f2bf(v);
        }
      }
    }
  }

  // ---- layer 2 (bf16 MFMA), bias, max over k, store
  {
    f32x4 acc[2][8];
    #pragma unroll
    for (int rr = 0; rr < 2; ++rr)
      #pragma unroll
      for (int ct = 0; ct < 8; ++ct)
        acc[rr][ct] = (f32x4){0.f, 0.f, 0.f, 0.f};

    #pragma unroll
    for (int ks = 0; ks < 4; ++ks) {
      int c0 = ks*32 + lg*8;
      bf16x8 a0 = *(const bf16x8*)&act[(rt0*16 + lr)*128 + (c0 ^ aswz)];
      bf16x8 a1 = *(const bf16x8*)&act[(rt1*16 + lr)*128 + (c0 ^ aswz)];
      #pragma unroll
      for (int ct = 0; ct < 8; ++ct) {
        int o = ct*16 + lr;
        bf16x8 bb = *(const bf16x8*)&W2bf[o*128 + c0];
        acc[0][ct] = __builtin_amdgcn_mfma_f32_16x16x32_bf16(a0, bb, acc[0][ct], 0, 0, 0);
        acc[1][ct] = __builtin_amdgcn_mfma_f32_16x16x32_bf16(a1, bb, acc[1][ct], 0, 0, 0);
      }
    }
    #pragma unroll
    for (int rr = 0; rr < 2; ++rr) {
      int p = rt0 + rr;   // point index within block (row-tile == point)
      #pragma unroll
      for (int ct = 0; ct < 8; ++ct) {
        int col = ct*16 + lr;
        float bias = b2s[col];
        float v0 = acc[rr][ct][0] + bias;
        float va = acc[rr][ct][1] + bias;
        float vb = acc[rr][ct][2] + bias;
        float vc = acc[rr][ct][3] + bias;
        float mx = fmaxf(fmaxf(v0, va), fmaxf(vb, vc));
        mx = fmaxf(mx, __shfl_xor(mx, 16));
        mx = fmaxf(mx, __shfl_xor(mx, 32));
        if (lg == 0) out[(size_t)(row_base + p)*128 + col] = mx;
      }
    }
  }
}

// ---------------------------------------------------------------- launch
extern "C" void kernel_launch(void* const* d_in, const int* in_sizes, int n_in,
                              void* d_out, int out_size, void* d_ws, size_t ws_size,
                              hipStream_t stream) {
  const float* xyz = (const float*)d_in[0];
  const float* W0  = (const float*)d_in[1];
  const float* b0  = (const float*)d_in[2];
  const float* W1  = (const float*)d_in[3];
  const float* b1  = (const float*)d_in[4];
  const float* W2  = (const float*)d_in[5];
  const float* b2  = (const float*)d_in[6];
  float* out = (float*)d_out;

  char* ws = (char*)d_ws;
  float4* xyzw     = (float4*)ws;                              // 512 KB
  float4* grouped4 = (float4*)(ws + (size_t)NROWS*16);         // 8 MB
  unsigned short* W1bf = (unsigned short*)(ws + (size_t)NROWS*16 + (size_t)NROWS*KNB*16);
  unsigned short* W2bf = W1bf + NC*NC;                         // 32 KB each

  prep_kernel<<<NROWS/256, 256, 0, stream>>>(xyz, W1, W2, xyzw, W1bf, W2bf);
  topk_kernel<<<NROWS/4, 256, 0, stream>>>(xyzw, grouped4);
  mlp_kernel<<<NROWS/8, 256, 0, stream>>>(grouped4, W0, b0, W1bf, b1, W2bf, b2, out);
}